// Round 2
// baseline (1243.250 us; speedup 1.0000x reference)
//
#include <hip/hip_runtime.h>
#include <hip/hip_bf16.h>
#include <stdint.h>

#define NDIM 128

// -------- detect int64 vs int32 edge buffer: int64 => all odd words zero ----
__global__ void detect_kernel(const unsigned* __restrict__ w, int* flag) {
    __shared__ int any_nonzero;
    if (threadIdx.x == 0) any_nonzero = 0;
    __syncthreads();
    int nz = 0;
    for (int k = threadIdx.x; k < 2048; k += 256) {
        if (w[2 * k + 1] != 0u) nz = 1;
    }
    if (nz) atomicOr(&any_nonzero, 1);
    __syncthreads();
    if (threadIdx.x == 0) *flag = any_nonzero ? 0 : 1;   // 1 = int64 layout
}

// -------- normalize edges into int32 src/dst arrays -------------------------
__global__ void normalize_kernel(const unsigned* __restrict__ w, const int* __restrict__ flag,
                                 int* __restrict__ srcn, int* __restrict__ dstn, int E) {
    int is64 = *flag;
    int i = blockIdx.x * blockDim.x + threadIdx.x;
    int stride = gridDim.x * blockDim.x;
    for (int e = i; e < E; e += stride) {
        if (is64) {
            srcn[e] = (int)w[(size_t)2 * e];
            dstn[e] = (int)w[(size_t)2 * E + (size_t)2 * e];
        } else {
            srcn[e] = (int)w[e];
            dstn[e] = (int)w[(size_t)E + e];
        }
    }
}

// -------- init: zero out accumulator, deg = 1 (self loop) -------------------
__global__ void init_kernel(float* out, int* deg, int out_n, int n_nodes) {
    int i = blockIdx.x * blockDim.x + threadIdx.x;
    int stride = gridDim.x * blockDim.x;
    for (int j = i; j < out_n; j += stride) out[j] = 0.f;
    for (int j = i; j < n_nodes; j += stride) deg[j] = 1;
}

// -------- degree count on dst ----------------------------------------------
__global__ void count_kernel(const int* __restrict__ dst, int* deg, int E) {
    int i = blockIdx.x * blockDim.x + threadIdx.x;
    int stride = gridDim.x * blockDim.x;
    for (int e = i; e < E; e += stride) atomicAdd(&deg[dst[e]], 1);
}

// -------- dis = rsqrt(deg) --------------------------------------------------
__global__ void dis_kernel(const int* __restrict__ deg, float* dis, int n) {
    int i = blockIdx.x * blockDim.x + threadIdx.x;
    if (i < n) dis[i] = rsqrtf((float)deg[i]);
}

// -------- h = x @ W (fp32, W staged in LDS) ---------------------------------
__global__ __launch_bounds__(128) void matmul_kernel(const float* __restrict__ x,
                                                     const float* __restrict__ W,
                                                     float* __restrict__ h, int n) {
    __shared__ float Ws[NDIM][NDIM];   // 64 KiB
    __shared__ float xs[NDIM];
    int t = threadIdx.x;
    for (int i = t; i < NDIM * NDIM; i += 128) Ws[i >> 7][i & 127] = W[i];
    __syncthreads();
    for (int row = blockIdx.x; row < n; row += gridDim.x) {
        xs[t] = x[(size_t)row * NDIM + t];
        __syncthreads();
        float acc = 0.f;
#pragma unroll
        for (int k = 0; k < NDIM; ++k) acc = fmaf(xs[k], Ws[k][t], acc);
        h[(size_t)row * NDIM + t] = acc;
        __syncthreads();
    }
}

// -------- edge scatter: out[dst] += h[src] * dis[src]*dis[dst] --------------
__global__ void scatter_kernel(const int* __restrict__ src, const int* __restrict__ dst,
                               const float* __restrict__ dis, const float* __restrict__ h,
                               float* out, int E) {
    long long total = (long long)E * 32;
    long long idx = (long long)blockIdx.x * blockDim.x + threadIdx.x;
    long long stride = (long long)gridDim.x * blockDim.x;
    for (; idx < total; idx += stride) {
        int e = (int)(idx >> 5);
        int c = (int)(idx & 31);
        int s = src[e], d = dst[e];
        float norm = dis[s] * dis[d];
        const float4 hv = ((const float4*)h)[(size_t)s * 32 + c];
        float* o = out + (size_t)d * NDIM + c * 4;
        atomicAdd(o + 0, hv.x * norm);
        atomicAdd(o + 1, hv.y * norm);
        atomicAdd(o + 2, hv.z * norm);
        atomicAdd(o + 3, hv.w * norm);
    }
}

// -------- finalize: +selfloop +bias, relu, partitionable-threefry dropout, +x
__device__ __forceinline__ unsigned rotl32(unsigned v, int d) {
    return (v << d) | (v >> (32 - d));
}

__global__ void finalize_kernel(float* out, const float* __restrict__ x,
                                const float* __restrict__ h, const float* __restrict__ dis,
                                const float* __restrict__ b, int total) {
    int i = blockIdx.x * blockDim.x + threadIdx.x;
    if (i >= total) return;
    // JAX partitionable threefry: counter = flat index i (uint64), key = (0, 42)
    // inputs: x0 = hi32(i) = 0, x1 = lo32(i) = i; 32-bit output = out1 ^ out2
    unsigned x0 = 0u, x1 = (unsigned)i;
    const unsigned ks0 = 0u, ks1 = 42u, ks2 = 0u ^ 42u ^ 0x1BD11BDAu;
    x0 += ks0; x1 += ks1;
#define RND(r) { x0 += x1; x1 = rotl32(x1, (r)); x1 ^= x0; }
    RND(13) RND(15) RND(26) RND(6)   x0 += ks1; x1 += ks2 + 1u;
    RND(17) RND(29) RND(16) RND(24)  x0 += ks2; x1 += ks0 + 2u;
    RND(13) RND(15) RND(26) RND(6)   x0 += ks0; x1 += ks1 + 3u;
    RND(17) RND(29) RND(16) RND(24)  x0 += ks1; x1 += ks2 + 4u;
    RND(13) RND(15) RND(26) RND(6)   x0 += ks2; x1 += ks0 + 5u;
#undef RND
    unsigned bits = x0 ^ x1;

    int nn = i >> 7, dd = i & 127;
    float di = dis[nn];
    float v = out[i] + h[i] * di * di + b[dd];
    v = fmaxf(v, 0.f);
    v = (bits >> 31) ? 0.f : v * 2.f;
    out[i] = v + x[i];
}

extern "C" void kernel_launch(void* const* d_in, const int* in_sizes, int n_in,
                              void* d_out, int out_size, void* d_ws, size_t ws_size,
                              hipStream_t stream) {
    const float* x = (const float*)d_in[0];
    const unsigned* edge_w = (const unsigned*)d_in[1];
    const float* W = (const float*)d_in[2];
    const float* b = (const float*)d_in[3];
    float* out = (float*)d_out;

    const int N = in_sizes[0] / NDIM;   // 50000
    const int E = in_sizes[1] / 2;      // 625000

    char* ws = (char*)d_ws;
    float* h    = (float*)ws;                                         // N*128 f32 = 25.6 MB
    int*   deg  = (int*)(ws + (size_t)N * NDIM * sizeof(float));      // N i32
    float* dis  = (float*)((char*)deg + (size_t)N * sizeof(int));     // N f32
    int*   srcn = (int*)((char*)dis + (size_t)N * sizeof(float));     // E i32
    int*   dstn = (int*)((char*)srcn + (size_t)E * sizeof(int));      // E i32
    int*   flag = (int*)((char*)dstn + (size_t)E * sizeof(int));      // 1 i32

    const int outN = N * NDIM;

    detect_kernel<<<1, 256, 0, stream>>>(edge_w, flag);
    normalize_kernel<<<(E + 255) / 256, 256, 0, stream>>>(edge_w, flag, srcn, dstn, E);

    init_kernel<<<2048, 256, 0, stream>>>(out, deg, outN, N);

    int cblocks = (E + 255) / 256; if (cblocks > 2048) cblocks = 2048;
    count_kernel<<<cblocks, 256, 0, stream>>>(dstn, deg, E);

    dis_kernel<<<(N + 255) / 256, 256, 0, stream>>>(deg, dis, N);

    matmul_kernel<<<1024, 128, 0, stream>>>(x, W, h, N);

    long long total = (long long)E * 32;
    int sblocks = (int)((total + 255) / 256);
    scatter_kernel<<<sblocks, 256, 0, stream>>>(srcn, dstn, dis, h, out, E);

    finalize_kernel<<<(outN + 255) / 256, 256, 0, stream>>>(out, x, h, dis, b, outN);
}

// Round 3
// 286.543 us; speedup vs baseline: 4.3388x; 4.3388x over previous
//
#include <hip/hip_runtime.h>
#include <hip/hip_bf16.h>
#include <stdint.h>

#define NDIM 128

// -------- detect int64 vs int32 edge buffer: int64 => all odd words zero ----
__global__ void detect_kernel(const unsigned* __restrict__ w, int* flag) {
    __shared__ int any_nonzero;
    if (threadIdx.x == 0) any_nonzero = 0;
    __syncthreads();
    int nz = 0;
    for (int k = threadIdx.x; k < 2048; k += 256) {
        if (w[2 * k + 1] != 0u) nz = 1;
    }
    if (nz) atomicOr(&any_nonzero, 1);
    __syncthreads();
    if (threadIdx.x == 0) *flag = any_nonzero ? 0 : 1;   // 1 = int64 layout
}

// -------- normalize edges into int32 src/dst arrays -------------------------
__global__ void normalize_kernel(const unsigned* __restrict__ w, const int* __restrict__ flag,
                                 int* __restrict__ srcn, int* __restrict__ dstn, int E) {
    int is64 = *flag;
    int i = blockIdx.x * blockDim.x + threadIdx.x;
    int stride = gridDim.x * blockDim.x;
    for (int e = i; e < E; e += stride) {
        if (is64) {
            srcn[e] = (int)w[(size_t)2 * e];
            dstn[e] = (int)w[(size_t)2 * E + (size_t)2 * e];
        } else {
            srcn[e] = (int)w[e];
            dstn[e] = (int)w[(size_t)E + e];
        }
    }
}

// -------- zero per-dst edge counts ------------------------------------------
__global__ void zero_kernel(int* cnt, int n) {
    int i = blockIdx.x * blockDim.x + threadIdx.x;
    if (i < n) cnt[i] = 0;
}

// -------- degree count on dst (edges only, no self loop) --------------------
__global__ void count_kernel(const int* __restrict__ dst, int* cnt, int E) {
    int i = blockIdx.x * blockDim.x + threadIdx.x;
    int stride = gridDim.x * blockDim.x;
    for (int e = i; e < E; e += stride) atomicAdd(&cnt[dst[e]], 1);
}

// -------- dis = rsqrt(cnt + 1)  (self loop included in degree) --------------
__global__ void dis_kernel(const int* __restrict__ cnt, float* dis, int n) {
    int i = blockIdx.x * blockDim.x + threadIdx.x;
    if (i < n) dis[i] = rsqrtf((float)(cnt[i] + 1));
}

// -------- scan step 1: per-256-block exclusive scan + block sums ------------
__global__ __launch_bounds__(256) void scan_block_kernel(const int* __restrict__ cnt,
                                                         int* __restrict__ off,
                                                         int* __restrict__ bsum, int N) {
    __shared__ int s[256];
    int t = threadIdx.x;
    int i = blockIdx.x * 256 + t;
    int v = (i < N) ? cnt[i] : 0;
    s[t] = v;
    __syncthreads();
    for (int d = 1; d < 256; d <<= 1) {
        int add = (t >= d) ? s[t - d] : 0;
        __syncthreads();
        s[t] += add;
        __syncthreads();
    }
    if (i < N) off[i] = s[t] - v;          // exclusive within block
    if (t == 255) bsum[blockIdx.x] = s[255];
}

// -------- scan step 2: exclusive scan of block sums (nb <= 256) -------------
__global__ __launch_bounds__(256) void scan_sums_kernel(int* bsum, int nb) {
    __shared__ int s[256];
    int t = threadIdx.x;
    int v = (t < nb) ? bsum[t] : 0;
    s[t] = v;
    __syncthreads();
    for (int d = 1; d < 256; d <<= 1) {
        int add = (t >= d) ? s[t - d] : 0;
        __syncthreads();
        s[t] += add;
        __syncthreads();
    }
    if (t < nb) bsum[t] = s[t] - v;        // exclusive
}

// -------- scan step 3: add block offsets, init cursor, set off[N] -----------
__global__ __launch_bounds__(256) void scan_add_kernel(int* __restrict__ off,
                                                       int* __restrict__ cursor,
                                                       const int* __restrict__ bsum,
                                                       int N, int E) {
    int i = blockIdx.x * 256 + threadIdx.x;
    if (i < N) {
        int o = off[i] + bsum[blockIdx.x];
        off[i] = o;
        cursor[i] = o;
    }
    if (i == 0) off[N] = E;
}

// -------- CSR fill: adj[pos] = src, bucketed by dst -------------------------
__global__ void fill_kernel(const int* __restrict__ src, const int* __restrict__ dst,
                            int* cursor, int* __restrict__ adj, int E) {
    int i = blockIdx.x * blockDim.x + threadIdx.x;
    int stride = gridDim.x * blockDim.x;
    for (int e = i; e < E; e += stride) {
        int pos = atomicAdd(&cursor[dst[e]], 1);
        adj[pos] = src[e];
    }
}

// -------- h = x @ W (fp32, W staged in LDS) ---------------------------------
__global__ __launch_bounds__(128) void matmul_kernel(const float* __restrict__ x,
                                                     const float* __restrict__ W,
                                                     float* __restrict__ h, int n) {
    __shared__ float Ws[NDIM][NDIM];   // 64 KiB
    __shared__ float xs[NDIM];
    int t = threadIdx.x;
    for (int i = t; i < NDIM * NDIM; i += 128) Ws[i >> 7][i & 127] = W[i];
    __syncthreads();
    for (int row = blockIdx.x; row < n; row += gridDim.x) {
        xs[t] = x[(size_t)row * NDIM + t];
        __syncthreads();
        float acc = 0.f;
#pragma unroll
        for (int k = 0; k < NDIM; ++k) acc = fmaf(xs[k], Ws[k][t], acc);
        h[(size_t)row * NDIM + t] = acc;
        __syncthreads();
    }
}

// -------- JAX partitionable threefry bits for counter (0, ctr), key (0,42) --
__device__ __forceinline__ unsigned rotl32(unsigned v, int d) {
    return (v << d) | (v >> (32 - d));
}
__device__ __forceinline__ unsigned tf_bits(unsigned ctr) {
    unsigned x0 = 0u, x1 = ctr;
    const unsigned ks0 = 0u, ks1 = 42u, ks2 = 0u ^ 42u ^ 0x1BD11BDAu;
    x0 += ks0; x1 += ks1;
#define RND(r) { x0 += x1; x1 = rotl32(x1, (r)); x1 ^= x0; }
    RND(13) RND(15) RND(26) RND(6)   x0 += ks1; x1 += ks2 + 1u;
    RND(17) RND(29) RND(16) RND(24)  x0 += ks2; x1 += ks0 + 2u;
    RND(13) RND(15) RND(26) RND(6)   x0 += ks0; x1 += ks1 + 3u;
    RND(17) RND(29) RND(16) RND(24)  x0 += ks1; x1 += ks2 + 4u;
    RND(13) RND(15) RND(26) RND(6)   x0 += ks2; x1 += ks0 + 5u;
#undef RND
    return x0 ^ x1;
}

// -------- gather + finalize: one wave per node ------------------------------
__global__ __launch_bounds__(256) void gather_kernel(const float* __restrict__ h,
                                                     const float* __restrict__ x,
                                                     const int* __restrict__ off,
                                                     const int* __restrict__ adj,
                                                     const float* __restrict__ dis,
                                                     const float* __restrict__ b,
                                                     float* __restrict__ out, int N) {
    int wave = (int)((blockIdx.x * (unsigned)blockDim.x + threadIdx.x) >> 6);
    int lane = threadIdx.x & 63;
    if (wave >= N) return;
    const int node = wave;
    const float dn = dis[node];
    const int c0 = lane * 2;

    // self-loop contribution
    float2 hv = ((const float2*)(h + (size_t)node * NDIM))[lane];
    float accx = hv.x * dn * dn;
    float accy = hv.y * dn * dn;

    int k0 = off[node], k1 = off[node + 1];
    for (int k = k0; k < k1; ++k) {
        int s = adj[k];
        float nrm = dis[s] * dn;
        float2 v = ((const float2*)(h + (size_t)s * NDIM))[lane];
        accx = fmaf(v.x, nrm, accx);
        accy = fmaf(v.y, nrm, accy);
    }

    // bias + relu
    float v0 = fmaxf(accx + b[c0], 0.f);
    float v1 = fmaxf(accy + b[c0 + 1], 0.f);

    // dropout (keep iff top bit clear), scale 2x
    unsigned i0 = (unsigned)(node * NDIM + c0);
    unsigned b0 = tf_bits(i0);
    unsigned b1 = tf_bits(i0 + 1u);
    v0 = (b0 >> 31) ? 0.f : v0 * 2.f;
    v1 = (b1 >> 31) ? 0.f : v1 * 2.f;

    // residual + store
    float2 xr = ((const float2*)(x + (size_t)node * NDIM))[lane];
    float2 o;
    o.x = v0 + xr.x;
    o.y = v1 + xr.y;
    ((float2*)(out + (size_t)node * NDIM))[lane] = o;
}

extern "C" void kernel_launch(void* const* d_in, const int* in_sizes, int n_in,
                              void* d_out, int out_size, void* d_ws, size_t ws_size,
                              hipStream_t stream) {
    const float* x = (const float*)d_in[0];
    const unsigned* edge_w = (const unsigned*)d_in[1];
    const float* W = (const float*)d_in[2];
    const float* b = (const float*)d_in[3];
    float* out = (float*)d_out;

    const int N = in_sizes[0] / NDIM;   // 50000
    const int E = in_sizes[1] / 2;      // 625000
    const int nb = (N + 255) / 256;     // scan blocks (196)

    char* ws = (char*)d_ws;
    float* h      = (float*)ws;                                        // N*128 f32
    int*   cnt    = (int*)(ws + (size_t)N * NDIM * sizeof(float));     // N
    float* dis    = (float*)((char*)cnt + (size_t)N * sizeof(int));    // N
    int*   off    = (int*)((char*)dis + (size_t)N * sizeof(float));    // N+1
    int*   cursor = (int*)((char*)off + (size_t)(N + 1) * sizeof(int));// N
    int*   bsum   = (int*)((char*)cursor + (size_t)N * sizeof(int));   // nb
    int*   srcn   = (int*)((char*)bsum + (size_t)256 * sizeof(int));   // E
    int*   dstn   = (int*)((char*)srcn + (size_t)E * sizeof(int));     // E
    int*   adj    = (int*)((char*)dstn + (size_t)E * sizeof(int));     // E
    int*   flag   = (int*)((char*)adj + (size_t)E * sizeof(int));      // 1

    detect_kernel<<<1, 256, 0, stream>>>(edge_w, flag);
    normalize_kernel<<<1024, 256, 0, stream>>>(edge_w, flag, srcn, dstn, E);

    zero_kernel<<<nb, 256, 0, stream>>>(cnt, N);
    count_kernel<<<1024, 256, 0, stream>>>(dstn, cnt, E);
    dis_kernel<<<nb, 256, 0, stream>>>(cnt, dis, N);

    scan_block_kernel<<<nb, 256, 0, stream>>>(cnt, off, bsum, N);
    scan_sums_kernel<<<1, 256, 0, stream>>>(bsum, nb);
    scan_add_kernel<<<nb, 256, 0, stream>>>(off, cursor, bsum, N, E);

    fill_kernel<<<1024, 256, 0, stream>>>(srcn, dstn, cursor, adj, E);

    matmul_kernel<<<1024, 128, 0, stream>>>(x, W, h, N);

    gather_kernel<<<(N + 3) / 4, 256, 0, stream>>>(h, x, off, adj, dis, b, out, N);
}

// Round 4
// 173.681 us; speedup vs baseline: 7.1582x; 1.6498x over previous
//
#include <hip/hip_runtime.h>
#include <hip/hip_bf16.h>
#include <stdint.h>

#define NDIM 128
#define LDK 136   // padded K stride (shorts) for Wt rows: 272B -> bank step 4

typedef __attribute__((ext_vector_type(8))) short bf16x8;
typedef __attribute__((ext_vector_type(4))) float f32x4;

__device__ __forceinline__ unsigned short f2bf(float f) {
    unsigned u = __float_as_uint(f);
    unsigned r = u + 0x7fffu + ((u >> 16) & 1u);   // round-to-nearest-even
    return (unsigned short)(r >> 16);
}
__device__ __forceinline__ float bf2f(unsigned short s) {
    return __uint_as_float(((unsigned)s) << 16);
}

// -------- detect int64 vs int32 edge buffer: int64 => all odd words zero ----
__global__ void detect_kernel(const unsigned* __restrict__ w, int* flag) {
    __shared__ int any_nonzero;
    if (threadIdx.x == 0) any_nonzero = 0;
    __syncthreads();
    int nz = 0;
    for (int k = threadIdx.x; k < 2048; k += 256) {
        if (w[2 * k + 1] != 0u) nz = 1;
    }
    if (nz) atomicOr(&any_nonzero, 1);
    __syncthreads();
    if (threadIdx.x == 0) *flag = any_nonzero ? 0 : 1;   // 1 = int64 layout
}

// -------- normalize edges into int32 src/dst arrays -------------------------
__global__ void normalize_kernel(const unsigned* __restrict__ w, const int* __restrict__ flag,
                                 int* __restrict__ srcn, int* __restrict__ dstn, int E) {
    int is64 = *flag;
    int i = blockIdx.x * blockDim.x + threadIdx.x;
    int stride = gridDim.x * blockDim.x;
    for (int e = i; e < E; e += stride) {
        if (is64) {
            srcn[e] = (int)w[(size_t)2 * e];
            dstn[e] = (int)w[(size_t)2 * E + (size_t)2 * e];
        } else {
            srcn[e] = (int)w[e];
            dstn[e] = (int)w[(size_t)E + e];
        }
    }
}

__global__ void zero_kernel(int* cnt, int n) {
    int i = blockIdx.x * blockDim.x + threadIdx.x;
    if (i < n) cnt[i] = 0;
}

__global__ void count_kernel(const int* __restrict__ dst, int* cnt, int E) {
    int i = blockIdx.x * blockDim.x + threadIdx.x;
    int stride = gridDim.x * blockDim.x;
    for (int e = i; e < E; e += stride) atomicAdd(&cnt[dst[e]], 1);
}

__global__ void dis_kernel(const int* __restrict__ cnt, float* dis, int n) {
    int i = blockIdx.x * blockDim.x + threadIdx.x;
    if (i < n) dis[i] = rsqrtf((float)(cnt[i] + 1));
}

// -------- exclusive scan (3 phases) ----------------------------------------
__global__ __launch_bounds__(256) void scan_block_kernel(const int* __restrict__ cnt,
                                                         int* __restrict__ off,
                                                         int* __restrict__ bsum, int N) {
    __shared__ int s[256];
    int t = threadIdx.x;
    int i = blockIdx.x * 256 + t;
    int v = (i < N) ? cnt[i] : 0;
    s[t] = v;
    __syncthreads();
    for (int d = 1; d < 256; d <<= 1) {
        int add = (t >= d) ? s[t - d] : 0;
        __syncthreads();
        s[t] += add;
        __syncthreads();
    }
    if (i < N) off[i] = s[t] - v;
    if (t == 255) bsum[blockIdx.x] = s[255];
}

__global__ __launch_bounds__(256) void scan_sums_kernel(int* bsum, int nb) {
    __shared__ int s[256];
    int t = threadIdx.x;
    int v = (t < nb) ? bsum[t] : 0;
    s[t] = v;
    __syncthreads();
    for (int d = 1; d < 256; d <<= 1) {
        int add = (t >= d) ? s[t - d] : 0;
        __syncthreads();
        s[t] += add;
        __syncthreads();
    }
    if (t < nb) bsum[t] = s[t] - v;
}

__global__ __launch_bounds__(256) void scan_add_kernel(int* __restrict__ off,
                                                       int* __restrict__ cursor,
                                                       const int* __restrict__ bsum,
                                                       int N, int E) {
    int i = blockIdx.x * 256 + threadIdx.x;
    if (i < N) {
        int o = off[i] + bsum[blockIdx.x];
        off[i] = o;
        cursor[i] = o;
    }
    if (i == 0) off[N] = E;
}

__global__ void fill_kernel(const int* __restrict__ src, const int* __restrict__ dst,
                            int* cursor, int* __restrict__ adj, int E) {
    int i = blockIdx.x * blockDim.x + threadIdx.x;
    int stride = gridDim.x * blockDim.x;
    for (int e = i; e < E; e += stride) {
        int pos = atomicAdd(&cursor[dst[e]], 1);
        adj[pos] = src[e];
    }
}

// -------- h' = (x @ W) * dis[row], stored bf16 (MFMA 16x16x32) --------------
__global__ __launch_bounds__(256) void gemm_kernel(const float* __restrict__ x,
                                                   const float* __restrict__ W,
                                                   const float* __restrict__ dis,
                                                   unsigned short* __restrict__ hp, int N) {
    __shared__ unsigned short Wt[NDIM][LDK];   // Wt[c][k] = bf16(W[k][c]), ~34 KiB
    int tid = threadIdx.x;
    for (int i = tid; i < NDIM * NDIM; i += 256) {
        int k = i >> 7, c = i & 127;
        Wt[c][k] = f2bf(W[i]);
    }
    __syncthreads();

    const int lane = tid & 63;
    const int wv = tid >> 6;
    const int rowbase = blockIdx.x * 64 + wv * 16;
    const int l15 = lane & 15;
    const int kg = lane >> 4;          // 0..3
    const int arow = rowbase + l15;

    // A fragments: a[s] = x[arow][s*32 + kg*8 .. +7] in bf16
    bf16x8 a[4];
#pragma unroll
    for (int s = 0; s < 4; ++s) {
        bf16x8 t;
        if (arow < N) {
            const float* p = x + (size_t)arow * NDIM + s * 32 + kg * 8;
            float4 f0 = *(const float4*)p;
            float4 f1 = *(const float4*)(p + 4);
            t[0] = (short)f2bf(f0.x); t[1] = (short)f2bf(f0.y);
            t[2] = (short)f2bf(f0.z); t[3] = (short)f2bf(f0.w);
            t[4] = (short)f2bf(f1.x); t[5] = (short)f2bf(f1.y);
            t[6] = (short)f2bf(f1.z); t[7] = (short)f2bf(f1.w);
        } else {
#pragma unroll
            for (int e = 0; e < 8; ++e) t[e] = 0;
        }
        a[s] = t;
    }

    f32x4 acc[8];
#pragma unroll
    for (int ct = 0; ct < 8; ++ct) acc[ct] = (f32x4){0.f, 0.f, 0.f, 0.f};

#pragma unroll
    for (int ct = 0; ct < 8; ++ct) {
#pragma unroll
        for (int s = 0; s < 4; ++s) {
            bf16x8 bb = *(const bf16x8*)&Wt[ct * 16 + l15][s * 32 + kg * 8];
            acc[ct] = __builtin_amdgcn_mfma_f32_16x16x32_bf16(a[s], bb, acc[ct], 0, 0, 0);
        }
    }

    // epilogue: C layout col = lane&15, row = kg*4 + j ; fold dis[row], store bf16
    const int r0 = rowbase + kg * 4;
    float dv[4];
#pragma unroll
    for (int j = 0; j < 4; ++j) dv[j] = (r0 + j < N) ? dis[r0 + j] : 0.f;
#pragma unroll
    for (int ct = 0; ct < 8; ++ct) {
        int col = ct * 16 + l15;
#pragma unroll
        for (int j = 0; j < 4; ++j) {
            int r = r0 + j;
            if (r < N) hp[(size_t)r * NDIM + col] = f2bf(acc[ct][j] * dv[j]);
        }
    }
}

// -------- JAX partitionable threefry bits, counter (0, ctr), key (0, 42) ----
__device__ __forceinline__ unsigned rotl32(unsigned v, int d) {
    return (v << d) | (v >> (32 - d));
}
__device__ __forceinline__ unsigned tf_bits(unsigned ctr) {
    unsigned x0 = 0u, x1 = ctr;
    const unsigned ks0 = 0u, ks1 = 42u, ks2 = 0u ^ 42u ^ 0x1BD11BDAu;
    x0 += ks0; x1 += ks1;
#define RND(r) { x0 += x1; x1 = rotl32(x1, (r)); x1 ^= x0; }
    RND(13) RND(15) RND(26) RND(6)   x0 += ks1; x1 += ks2 + 1u;
    RND(17) RND(29) RND(16) RND(24)  x0 += ks2; x1 += ks0 + 2u;
    RND(13) RND(15) RND(26) RND(6)   x0 += ks0; x1 += ks1 + 3u;
    RND(17) RND(29) RND(16) RND(24)  x0 += ks1; x1 += ks2 + 4u;
    RND(13) RND(15) RND(26) RND(6)   x0 += ks2; x1 += ks0 + 5u;
#undef RND
    return x0 ^ x1;
}

// -------- gather + finalize: one wave per node, h' is bf16 ------------------
__global__ __launch_bounds__(256) void gather_kernel(const unsigned short* __restrict__ hp,
                                                     const float* __restrict__ x,
                                                     const int* __restrict__ off,
                                                     const int* __restrict__ adj,
                                                     const float* __restrict__ dis,
                                                     const float* __restrict__ b,
                                                     float* __restrict__ out, int N) {
    int wave = (int)((blockIdx.x * 256u + threadIdx.x) >> 6);
    if (wave >= N) return;
    const int lane = threadIdx.x & 63;
    const int node = wave;
    const float dn = dis[node];
    const int c0 = lane * 2;

    // self-loop: h'[node] (already contains dis[node])
    unsigned hv = *(const unsigned*)(hp + (size_t)node * NDIM + c0);
    float ax = bf2f((unsigned short)hv);
    float ay = bf2f((unsigned short)(hv >> 16));

    int k0 = off[node], k1 = off[node + 1];
    for (int k = k0; k < k1; ++k) {
        int s = adj[k];
        unsigned v = *(const unsigned*)(hp + (size_t)s * NDIM + c0);
        ax += bf2f((unsigned short)v);
        ay += bf2f((unsigned short)(v >> 16));
    }

    float v0 = fmaxf(fmaf(dn, ax, b[c0]), 0.f);
    float v1 = fmaxf(fmaf(dn, ay, b[c0 + 1]), 0.f);

    unsigned i0 = (unsigned)(node * NDIM + c0);
    unsigned bb0 = tf_bits(i0);
    unsigned bb1 = tf_bits(i0 + 1u);
    v0 = (bb0 >> 31) ? 0.f : v0 * 2.f;
    v1 = (bb1 >> 31) ? 0.f : v1 * 2.f;

    float2 xr = ((const float2*)(x + (size_t)node * NDIM))[lane];
    float2 o;
    o.x = v0 + xr.x;
    o.y = v1 + xr.y;
    ((float2*)(out + (size_t)node * NDIM))[lane] = o;
}

extern "C" void kernel_launch(void* const* d_in, const int* in_sizes, int n_in,
                              void* d_out, int out_size, void* d_ws, size_t ws_size,
                              hipStream_t stream) {
    const float* x = (const float*)d_in[0];
    const unsigned* edge_w = (const unsigned*)d_in[1];
    const float* W = (const float*)d_in[2];
    const float* b = (const float*)d_in[3];
    float* out = (float*)d_out;

    const int N = in_sizes[0] / NDIM;   // 50000
    const int E = in_sizes[1] / 2;      // 625000
    const int nb = (N + 255) / 256;     // scan blocks (196)

    char* ws = (char*)d_ws;
    unsigned short* hp = (unsigned short*)ws;                          // N*128 bf16
    int*   cnt    = (int*)(ws + (size_t)N * NDIM * sizeof(short));     // N
    float* dis    = (float*)((char*)cnt + (size_t)N * sizeof(int));    // N
    int*   off    = (int*)((char*)dis + (size_t)N * sizeof(float));    // N+1
    int*   cursor = (int*)((char*)off + (size_t)(N + 1) * sizeof(int));// N
    int*   bsum   = (int*)((char*)cursor + (size_t)N * sizeof(int));   // 256
    int*   srcn   = (int*)((char*)bsum + (size_t)256 * sizeof(int));   // E
    int*   dstn   = (int*)((char*)srcn + (size_t)E * sizeof(int));     // E
    int*   adj    = (int*)((char*)dstn + (size_t)E * sizeof(int));     // E
    int*   flag   = (int*)((char*)adj + (size_t)E * sizeof(int));      // 1

    detect_kernel<<<1, 256, 0, stream>>>(edge_w, flag);
    normalize_kernel<<<1024, 256, 0, stream>>>(edge_w, flag, srcn, dstn, E);

    zero_kernel<<<nb, 256, 0, stream>>>(cnt, N);
    count_kernel<<<1024, 256, 0, stream>>>(dstn, cnt, E);
    dis_kernel<<<nb, 256, 0, stream>>>(cnt, dis, N);

    scan_block_kernel<<<nb, 256, 0, stream>>>(cnt, off, bsum, N);
    scan_sums_kernel<<<1, 256, 0, stream>>>(bsum, nb);
    scan_add_kernel<<<nb, 256, 0, stream>>>(off, cursor, bsum, N, E);

    fill_kernel<<<1024, 256, 0, stream>>>(srcn, dstn, cursor, adj, E);

    gemm_kernel<<<(N + 63) / 64, 256, 0, stream>>>(x, W, dis, hp, N);

    gather_kernel<<<(N + 3) / 4, 256, 0, stream>>>(hp, x, off, adj, dis, b, out, N);
}

// Round 5
// 139.423 us; speedup vs baseline: 8.9171x; 1.2457x over previous
//
#include <hip/hip_runtime.h>
#include <hip/hip_bf16.h>
#include <stdint.h>

#define NDIM 128
#define LDK 136   // padded K stride (shorts) for Wt rows

typedef __attribute__((ext_vector_type(8))) short bf16x8;
typedef __attribute__((ext_vector_type(4))) float f32x4;

__device__ __forceinline__ unsigned short f2bf(float f) {
    unsigned u = __float_as_uint(f);
    unsigned r = u + 0x7fffu + ((u >> 16) & 1u);   // round-to-nearest-even
    return (unsigned short)(r >> 16);
}
__device__ __forceinline__ float bf2f(unsigned short s) {
    return __uint_as_float(((unsigned)s) << 16);
}

// -------- detect int64 vs int32 edge buffer: int64 => all odd words zero ----
__global__ void detect_kernel(const unsigned* __restrict__ w, int* flag) {
    __shared__ int any_nonzero;
    if (threadIdx.x == 0) any_nonzero = 0;
    __syncthreads();
    int nz = 0;
    for (int k = threadIdx.x; k < 2048; k += 256) {
        if (w[2 * k + 1] != 0u) nz = 1;
    }
    if (nz) atomicOr(&any_nonzero, 1);
    __syncthreads();
    if (threadIdx.x == 0) *flag = any_nonzero ? 0 : 1;   // 1 = int64 layout
}

// -------- normalize edges into int32 src/dst arrays -------------------------
__global__ void normalize_kernel(const unsigned* __restrict__ w, const int* __restrict__ flag,
                                 int* __restrict__ srcn, int* __restrict__ dstn, int E) {
    int is64 = *flag;
    int i = blockIdx.x * blockDim.x + threadIdx.x;
    int stride = gridDim.x * blockDim.x;
    for (int e = i; e < E; e += stride) {
        if (is64) {
            srcn[e] = (int)w[(size_t)2 * e];
            dstn[e] = (int)w[(size_t)2 * E + (size_t)2 * e];
        } else {
            srcn[e] = (int)w[e];
            dstn[e] = (int)w[(size_t)E + e];
        }
    }
}

__global__ void zero_kernel(int* cnt, int n) {
    int i = blockIdx.x * blockDim.x + threadIdx.x;
    if (i < n) cnt[i] = 0;
}

__global__ void count_kernel(const int* __restrict__ dst, int* cnt, int E) {
    int i = blockIdx.x * blockDim.x + threadIdx.x;
    int stride = gridDim.x * blockDim.x;
    for (int e = i; e < E; e += stride) atomicAdd(&cnt[dst[e]], 1);
}

__global__ void dis_kernel(const int* __restrict__ cnt, float* dis, int n) {
    int i = blockIdx.x * blockDim.x + threadIdx.x;
    if (i < n) dis[i] = rsqrtf((float)(cnt[i] + 1));
}

// -------- exclusive scan (3 phases) ----------------------------------------
__global__ __launch_bounds__(256) void scan_block_kernel(const int* __restrict__ cnt,
                                                         int* __restrict__ off,
                                                         int* __restrict__ bsum, int N) {
    __shared__ int s[256];
    int t = threadIdx.x;
    int i = blockIdx.x * 256 + t;
    int v = (i < N) ? cnt[i] : 0;
    s[t] = v;
    __syncthreads();
    for (int d = 1; d < 256; d <<= 1) {
        int add = (t >= d) ? s[t - d] : 0;
        __syncthreads();
        s[t] += add;
        __syncthreads();
    }
    if (i < N) off[i] = s[t] - v;
    if (t == 255) bsum[blockIdx.x] = s[255];
}

__global__ __launch_bounds__(256) void scan_sums_kernel(int* bsum, int nb) {
    __shared__ int s[256];
    int t = threadIdx.x;
    int v = (t < nb) ? bsum[t] : 0;
    s[t] = v;
    __syncthreads();
    for (int d = 1; d < 256; d <<= 1) {
        int add = (t >= d) ? s[t - d] : 0;
        __syncthreads();
        s[t] += add;
        __syncthreads();
    }
    if (t < nb) bsum[t] = s[t] - v;
}

__global__ __launch_bounds__(256) void scan_add_kernel(int* __restrict__ off,
                                                       int* __restrict__ cursor,
                                                       const int* __restrict__ bsum,
                                                       int N, int E) {
    int i = blockIdx.x * 256 + threadIdx.x;
    if (i < N) {
        int o = off[i] + bsum[blockIdx.x];
        off[i] = o;
        cursor[i] = o;
    }
    if (i == 0) off[N] = E;
}

__global__ void fill_kernel(const int* __restrict__ src, const int* __restrict__ dst,
                            int* cursor, int* __restrict__ adj, int E) {
    int i = blockIdx.x * blockDim.x + threadIdx.x;
    int stride = gridDim.x * blockDim.x;
    for (int e = i; e < E; e += stride) {
        int pos = atomicAdd(&cursor[dst[e]], 1);
        adj[pos] = src[e];
    }
}

// -------- h' = (x @ W) * dis[row], stored bf16 (MFMA 16x16x32) --------------
__global__ __launch_bounds__(256) void gemm_kernel(const float* __restrict__ x,
                                                   const float* __restrict__ W,
                                                   const float* __restrict__ dis,
                                                   unsigned short* __restrict__ hp, int N) {
    __shared__ unsigned short Wt[NDIM][LDK];   // Wt[c][k] = bf16(W[k][c])
    int tid = threadIdx.x;
    for (int i = tid; i < NDIM * NDIM; i += 256) {
        int k = i >> 7, c = i & 127;
        Wt[c][k] = f2bf(W[i]);
    }
    __syncthreads();

    const int lane = tid & 63;
    const int wv = tid >> 6;
    const int rowbase = blockIdx.x * 64 + wv * 16;
    const int l15 = lane & 15;
    const int kg = lane >> 4;          // 0..3
    const int arow = rowbase + l15;

    bf16x8 a[4];
#pragma unroll
    for (int s = 0; s < 4; ++s) {
        bf16x8 t;
        if (arow < N) {
            const float* p = x + (size_t)arow * NDIM + s * 32 + kg * 8;
            float4 f0 = *(const float4*)p;
            float4 f1 = *(const float4*)(p + 4);
            t[0] = (short)f2bf(f0.x); t[1] = (short)f2bf(f0.y);
            t[2] = (short)f2bf(f0.z); t[3] = (short)f2bf(f0.w);
            t[4] = (short)f2bf(f1.x); t[5] = (short)f2bf(f1.y);
            t[6] = (short)f2bf(f1.z); t[7] = (short)f2bf(f1.w);
        } else {
#pragma unroll
            for (int e = 0; e < 8; ++e) t[e] = 0;
        }
        a[s] = t;
    }

    f32x4 acc[8];
#pragma unroll
    for (int ct = 0; ct < 8; ++ct) acc[ct] = (f32x4){0.f, 0.f, 0.f, 0.f};

#pragma unroll
    for (int ct = 0; ct < 8; ++ct) {
#pragma unroll
        for (int s = 0; s < 4; ++s) {
            bf16x8 bb = *(const bf16x8*)&Wt[ct * 16 + l15][s * 32 + kg * 8];
            acc[ct] = __builtin_amdgcn_mfma_f32_16x16x32_bf16(a[s], bb, acc[ct], 0, 0, 0);
        }
    }

    const int r0 = rowbase + kg * 4;
    float dv[4];
#pragma unroll
    for (int j = 0; j < 4; ++j) dv[j] = (r0 + j < N) ? dis[r0 + j] : 0.f;
#pragma unroll
    for (int ct = 0; ct < 8; ++ct) {
        int col = ct * 16 + l15;
#pragma unroll
        for (int j = 0; j < 4; ++j) {
            int r = r0 + j;
            if (r < N) hp[(size_t)r * NDIM + col] = f2bf(acc[ct][j] * dv[j]);
        }
    }
}

// -------- JAX partitionable threefry bits, counter (0, ctr), key (0, 42) ----
__device__ __forceinline__ unsigned rotl32(unsigned v, int d) {
    return (v << d) | (v >> (32 - d));
}
__device__ __forceinline__ unsigned tf_bits(unsigned ctr) {
    unsigned x0 = 0u, x1 = ctr;
    const unsigned ks0 = 0u, ks1 = 42u, ks2 = 0u ^ 42u ^ 0x1BD11BDAu;
    x0 += ks0; x1 += ks1;
#define RND(r) { x0 += x1; x1 = rotl32(x1, (r)); x1 ^= x0; }
    RND(13) RND(15) RND(26) RND(6)   x0 += ks1; x1 += ks2 + 1u;
    RND(17) RND(29) RND(16) RND(24)  x0 += ks2; x1 += ks0 + 2u;
    RND(13) RND(15) RND(26) RND(6)   x0 += ks0; x1 += ks1 + 3u;
    RND(17) RND(29) RND(16) RND(24)  x0 += ks1; x1 += ks2 + 4u;
    RND(13) RND(15) RND(26) RND(6)   x0 += ks2; x1 += ks0 + 5u;
#undef RND
    return x0 ^ x1;
}

// -------- gather + finalize: one wave per node, 4-deep MLP ------------------
__global__ __launch_bounds__(256) void gather_kernel(const unsigned short* __restrict__ hp,
                                                     const float* __restrict__ x,
                                                     const int* __restrict__ off,
                                                     const int* __restrict__ adj,
                                                     const float* __restrict__ dis,
                                                     const float* __restrict__ b,
                                                     float* __restrict__ out, int N) {
    int wave = (int)((blockIdx.x * 256u + threadIdx.x) >> 6);
    if (wave >= N) return;
    const int lane = threadIdx.x & 63;
    const int node = wave;
    const float dn = dis[node];
    const int c0 = lane * 2;
    const unsigned short* hpc = hp + c0;

    // self-loop: h'[node] (already contains dis[node])
    unsigned hv = *(const unsigned*)(hpc + (size_t)node * NDIM);
    float ax0 = bf2f((unsigned short)hv), ay0 = bf2f((unsigned short)(hv >> 16));
    float ax1 = 0.f, ay1 = 0.f, ax2 = 0.f, ay2 = 0.f, ax3 = 0.f, ay3 = 0.f;

    int k0 = off[node], k1 = off[node + 1];
    int kbase = k0;
    while (kbase < k1) {
        int nb = k1 - kbase; if (nb > 64) nb = 64;
        // cooperative batch-load of adjacency indices (one coalesced load)
        int myadj = (kbase + lane < k1) ? adj[kbase + lane] : 0;
        int j = 0;
        for (; j + 4 <= nb; j += 4) {
            int s0 = __shfl(myadj, j);
            int s1 = __shfl(myadj, j + 1);
            int s2 = __shfl(myadj, j + 2);
            int s3 = __shfl(myadj, j + 3);
            unsigned v0 = *(const unsigned*)(hpc + (size_t)s0 * NDIM);
            unsigned v1 = *(const unsigned*)(hpc + (size_t)s1 * NDIM);
            unsigned v2 = *(const unsigned*)(hpc + (size_t)s2 * NDIM);
            unsigned v3 = *(const unsigned*)(hpc + (size_t)s3 * NDIM);
            ax0 += bf2f((unsigned short)v0); ay0 += bf2f((unsigned short)(v0 >> 16));
            ax1 += bf2f((unsigned short)v1); ay1 += bf2f((unsigned short)(v1 >> 16));
            ax2 += bf2f((unsigned short)v2); ay2 += bf2f((unsigned short)(v2 >> 16));
            ax3 += bf2f((unsigned short)v3); ay3 += bf2f((unsigned short)(v3 >> 16));
        }
        for (; j < nb; ++j) {
            int s = __shfl(myadj, j);
            unsigned v = *(const unsigned*)(hpc + (size_t)s * NDIM);
            ax0 += bf2f((unsigned short)v); ay0 += bf2f((unsigned short)(v >> 16));
        }
        kbase += nb;
    }

    float ax = (ax0 + ax1) + (ax2 + ax3);
    float ay = (ay0 + ay1) + (ay2 + ay3);

    float v0 = fmaxf(fmaf(dn, ax, b[c0]), 0.f);
    float v1 = fmaxf(fmaf(dn, ay, b[c0 + 1]), 0.f);

    unsigned i0 = (unsigned)(node * NDIM + c0);
    unsigned bb0 = tf_bits(i0);
    unsigned bb1 = tf_bits(i0 + 1u);
    v0 = (bb0 >> 31) ? 0.f : v0 * 2.f;
    v1 = (bb1 >> 31) ? 0.f : v1 * 2.f;

    float2 xr = ((const float2*)(x + (size_t)node * NDIM))[lane];
    float2 o;
    o.x = v0 + xr.x;
    o.y = v1 + xr.y;
    ((float2*)(out + (size_t)node * NDIM))[lane] = o;
}

extern "C" void kernel_launch(void* const* d_in, const int* in_sizes, int n_in,
                              void* d_out, int out_size, void* d_ws, size_t ws_size,
                              hipStream_t stream) {
    const float* x = (const float*)d_in[0];
    const unsigned* edge_w = (const unsigned*)d_in[1];
    const float* W = (const float*)d_in[2];
    const float* b = (const float*)d_in[3];
    float* out = (float*)d_out;

    const int N = in_sizes[0] / NDIM;   // 50000
    const int E = in_sizes[1] / 2;      // 625000
    const int nb = (N + 255) / 256;     // scan blocks (196)

    char* ws = (char*)d_ws;
    unsigned short* hp = (unsigned short*)ws;                          // N*128 bf16
    int*   cnt    = (int*)(ws + (size_t)N * NDIM * sizeof(short));     // N
    float* dis    = (float*)((char*)cnt + (size_t)N * sizeof(int));    // N
    int*   off    = (int*)((char*)dis + (size_t)N * sizeof(float));    // N+1
    int*   cursor = (int*)((char*)off + (size_t)(N + 1) * sizeof(int));// N
    int*   bsum   = (int*)((char*)cursor + (size_t)N * sizeof(int));   // 256
    int*   srcn   = (int*)((char*)bsum + (size_t)256 * sizeof(int));   // E
    int*   dstn   = (int*)((char*)srcn + (size_t)E * sizeof(int));     // E
    int*   adj    = (int*)((char*)dstn + (size_t)E * sizeof(int));     // E
    int*   flag   = (int*)((char*)adj + (size_t)E * sizeof(int));      // 1

    detect_kernel<<<1, 256, 0, stream>>>(edge_w, flag);
    normalize_kernel<<<1024, 256, 0, stream>>>(edge_w, flag, srcn, dstn, E);

    zero_kernel<<<nb, 256, 0, stream>>>(cnt, N);
    count_kernel<<<1024, 256, 0, stream>>>(dstn, cnt, E);
    dis_kernel<<<nb, 256, 0, stream>>>(cnt, dis, N);

    scan_block_kernel<<<nb, 256, 0, stream>>>(cnt, off, bsum, N);
    scan_sums_kernel<<<1, 256, 0, stream>>>(bsum, nb);
    scan_add_kernel<<<nb, 256, 0, stream>>>(off, cursor, bsum, N, E);

    fill_kernel<<<1024, 256, 0, stream>>>(srcn, dstn, cursor, adj, E);

    gemm_kernel<<<(N + 63) / 64, 256, 0, stream>>>(x, W, dis, hp, N);

    gather_kernel<<<(N + 3) / 4, 256, 0, stream>>>(hp, x, off, adj, dis, b, out, N);
}

// Round 6
// 84.275 us; speedup vs baseline: 14.7523x; 1.6544x over previous
//
#include <hip/hip_runtime.h>
#include <hip/hip_bf16.h>
#include <stdint.h>

#define NDIM 128
#define LDK 136      // padded K stride (shorts) for Wt rows
#define BSH 9        // bucket shift: 512 nodes per bucket
#define NB_A 1024    // bucketing grid
#define BCAP 9216    // per-bucket staging capacity (expected ~6400)

typedef __attribute__((ext_vector_type(8))) short bf16x8;
typedef __attribute__((ext_vector_type(4))) float f32x4;

__device__ __forceinline__ unsigned short f2bf(float f) {
    unsigned u = __float_as_uint(f);
    unsigned r = u + 0x7fffu + ((u >> 16) & 1u);   // round-to-nearest-even
    return (unsigned short)(r >> 16);
}
__device__ __forceinline__ float bf2f(unsigned short s) {
    return __uint_as_float(((unsigned)s) << 16);
}

// -------- edge accessor handling int64 vs int32 raw layout ------------------
__device__ __forceinline__ void load_edge(const unsigned* __restrict__ w, int is64, int E,
                                          int e, int& s, int& d) {
    if (is64) {
        s = (int)w[(size_t)2 * e];
        d = (int)w[(size_t)2 * E + (size_t)2 * e];
    } else {
        s = (int)w[e];
        d = (int)w[(size_t)E + e];
    }
}

// -------- detect int64 vs int32 edge buffer: int64 => all odd words zero ----
__global__ void detect_kernel(const unsigned* __restrict__ w, int* flag) {
    __shared__ int any_nonzero;
    if (threadIdx.x == 0) any_nonzero = 0;
    __syncthreads();
    int nz = 0;
    for (int k = threadIdx.x; k < 2048; k += 256) {
        if (w[2 * k + 1] != 0u) nz = 1;
    }
    if (nz) atomicOr(&any_nonzero, 1);
    __syncthreads();
    if (threadIdx.x == 0) *flag = any_nonzero ? 0 : 1;   // 1 = int64 layout
}

// -------- per-block bucket histogram (LDS privatized) -----------------------
__global__ __launch_bounds__(256) void hist_kernel(const unsigned* __restrict__ w,
                                                   const int* __restrict__ flag,
                                                   int* __restrict__ hist,
                                                   int E, int nbuck, int chunk) {
    __shared__ int h[128];
    int t = threadIdx.x;
    if (t < 128) h[t] = 0;
    __syncthreads();
    int is64 = *flag;
    int lo = blockIdx.x * chunk;
    int hi = lo + chunk; if (hi > E) hi = E;
    for (int e = lo + t; e < hi; e += 256) {
        int s, d; load_edge(w, is64, E, e, s, d);
        atomicAdd(&h[d >> BSH], 1);
    }
    __syncthreads();
    if (t < nbuck) hist[(size_t)t * gridDim.x + blockIdx.x] = h[t];
}

// -------- scan of each bucket's 1024 block-counts (one block per bucket) ----
__global__ __launch_bounds__(1024) void scanhist_kernel(int* __restrict__ hist,
                                                        int* __restrict__ btot, int NB) {
    __shared__ int s[1024];
    int t = threadIdx.x;
    size_t base = (size_t)blockIdx.x * NB;
    int v = hist[base + t];
    s[t] = v;
    __syncthreads();
    for (int d = 1; d < 1024; d <<= 1) {
        int add = (t >= d) ? s[t - d] : 0;
        __syncthreads();
        s[t] += add;
        __syncthreads();
    }
    hist[base + t] = s[t] - v;            // exclusive within bucket
    if (t == 1023) btot[blockIdx.x] = s[1023];
}

// -------- scan of bucket totals + off[N] = E --------------------------------
__global__ __launch_bounds__(128) void scanbuck_kernel(const int* __restrict__ btot,
                                                       int* __restrict__ bbase, int nbuck,
                                                       int* __restrict__ off, int N, int E) {
    __shared__ int s[128];
    int t = threadIdx.x;
    int v = (t < nbuck) ? btot[t] : 0;
    s[t] = v;
    __syncthreads();
    for (int d = 1; d < 128; d <<= 1) {
        int add = (t >= d) ? s[t - d] : 0;
        __syncthreads();
        s[t] += add;
        __syncthreads();
    }
    if (t < nbuck) bbase[t] = s[t] - v;   // exclusive
    if (t == 0) off[N] = E;
}

// -------- bucket scatter: packed (src<<9 | local) into reserved runs --------
__global__ __launch_bounds__(256) void bucket_kernel(const unsigned* __restrict__ w,
                                                     const int* __restrict__ flag,
                                                     const int* __restrict__ hist,
                                                     const int* __restrict__ bbase,
                                                     unsigned* __restrict__ ebuf,
                                                     int E, int nbuck, int chunk) {
    __shared__ int cur[128];
    int t = threadIdx.x;
    if (t < nbuck) cur[t] = bbase[t] + hist[(size_t)t * gridDim.x + blockIdx.x];
    __syncthreads();
    int is64 = *flag;
    int lo = blockIdx.x * chunk;
    int hi = lo + chunk; if (hi > E) hi = E;
    for (int e = lo + t; e < hi; e += 256) {
        int s, d; load_edge(w, is64, E, e, s, d);
        int b = d >> BSH;
        int p = atomicAdd(&cur[b], 1);    // LDS atomic
        ebuf[p] = ((unsigned)s << BSH) | (unsigned)(d & ((1 << BSH) - 1));
    }
}

// -------- per-bucket CSR build: cnt/dis/off/adj, all coalesced --------------
__global__ __launch_bounds__(512) void csr_kernel(const unsigned* __restrict__ ebuf,
                                                  const int* __restrict__ bbase,
                                                  const int* __restrict__ btot,
                                                  int* __restrict__ adj,
                                                  int* __restrict__ off,
                                                  float* __restrict__ dis,
                                                  int N) {
    __shared__ int lcnt[512];
    __shared__ int lscan[512];
    __shared__ int cur[512];
    __shared__ int tile[BCAP];
    int b = blockIdx.x, t = threadIdx.x;
    int start = bbase[b], cnt = btot[b];
    lcnt[t] = 0;
    __syncthreads();
    for (int i = t; i < cnt; i += 512) atomicAdd(&lcnt[ebuf[start + i] & 511], 1);
    __syncthreads();
    int v = lcnt[t];
    lscan[t] = v;
    __syncthreads();
    for (int d = 1; d < 512; d <<= 1) {
        int add = (t >= d) ? lscan[t - d] : 0;
        __syncthreads();
        lscan[t] += add;
        __syncthreads();
    }
    int ex = lscan[t] - v;                 // exclusive
    int node = (b << BSH) + t;
    if (node < N) {
        off[node] = start + ex;
        dis[node] = rsqrtf((float)(v + 1));
    }
    cur[t] = ex;
    __syncthreads();
    if (cnt <= BCAP) {
        for (int i = t; i < cnt; i += 512) {
            unsigned wo = ebuf[start + i];
            int p = atomicAdd(&cur[wo & 511], 1);
            tile[p] = (int)(wo >> BSH);
        }
        __syncthreads();
        for (int i = t; i < cnt; i += 512) adj[start + i] = tile[i];
    } else {                               // overflow fallback (never for this input)
        for (int i = t; i < cnt; i += 512) {
            unsigned wo = ebuf[start + i];
            int p = atomicAdd(&cur[wo & 511], 1);
            adj[start + p] = (int)(wo >> BSH);
        }
    }
}

// -------- h' = (x @ W) * dis[row], stored bf16 (MFMA 16x16x32) --------------
__global__ __launch_bounds__(256) void gemm_kernel(const float* __restrict__ x,
                                                   const float* __restrict__ W,
                                                   const float* __restrict__ dis,
                                                   unsigned short* __restrict__ hp, int N) {
    __shared__ unsigned short Wt[NDIM][LDK];   // Wt[c][k] = bf16(W[k][c])
    int tid = threadIdx.x;
    for (int i = tid; i < NDIM * NDIM; i += 256) {
        int k = i >> 7, c = i & 127;
        Wt[c][k] = f2bf(W[i]);
    }
    __syncthreads();

    const int lane = tid & 63;
    const int wv = tid >> 6;
    const int rowbase = blockIdx.x * 64 + wv * 16;
    const int l15 = lane & 15;
    const int kg = lane >> 4;          // 0..3
    const int arow = rowbase + l15;

    bf16x8 a[4];
#pragma unroll
    for (int s = 0; s < 4; ++s) {
        bf16x8 tt;
        if (arow < N) {
            const float* p = x + (size_t)arow * NDIM + s * 32 + kg * 8;
            float4 f0 = *(const float4*)p;
            float4 f1 = *(const float4*)(p + 4);
            tt[0] = (short)f2bf(f0.x); tt[1] = (short)f2bf(f0.y);
            tt[2] = (short)f2bf(f0.z); tt[3] = (short)f2bf(f0.w);
            tt[4] = (short)f2bf(f1.x); tt[5] = (short)f2bf(f1.y);
            tt[6] = (short)f2bf(f1.z); tt[7] = (short)f2bf(f1.w);
        } else {
#pragma unroll
            for (int e = 0; e < 8; ++e) tt[e] = 0;
        }
        a[s] = tt;
    }

    f32x4 acc[8];
#pragma unroll
    for (int ct = 0; ct < 8; ++ct) acc[ct] = (f32x4){0.f, 0.f, 0.f, 0.f};

#pragma unroll
    for (int ct = 0; ct < 8; ++ct) {
#pragma unroll
        for (int s = 0; s < 4; ++s) {
            bf16x8 bb = *(const bf16x8*)&Wt[ct * 16 + l15][s * 32 + kg * 8];
            acc[ct] = __builtin_amdgcn_mfma_f32_16x16x32_bf16(a[s], bb, acc[ct], 0, 0, 0);
        }
    }

    const int r0 = rowbase + kg * 4;
    float dv[4];
#pragma unroll
    for (int j = 0; j < 4; ++j) dv[j] = (r0 + j < N) ? dis[r0 + j] : 0.f;
#pragma unroll
    for (int ct = 0; ct < 8; ++ct) {
        int col = ct * 16 + l15;
#pragma unroll
        for (int j = 0; j < 4; ++j) {
            int r = r0 + j;
            if (r < N) hp[(size_t)r * NDIM + col] = f2bf(acc[ct][j] * dv[j]);
        }
    }
}

// -------- JAX partitionable threefry bits, counter (0, ctr), key (0, 42) ----
__device__ __forceinline__ unsigned rotl32(unsigned v, int d) {
    return (v << d) | (v >> (32 - d));
}
__device__ __forceinline__ unsigned tf_bits(unsigned ctr) {
    unsigned x0 = 0u, x1 = ctr;
    const unsigned ks0 = 0u, ks1 = 42u, ks2 = 0u ^ 42u ^ 0x1BD11BDAu;
    x0 += ks0; x1 += ks1;
#define RND(r) { x0 += x1; x1 = rotl32(x1, (r)); x1 ^= x0; }
    RND(13) RND(15) RND(26) RND(6)   x0 += ks1; x1 += ks2 + 1u;
    RND(17) RND(29) RND(16) RND(24)  x0 += ks2; x1 += ks0 + 2u;
    RND(13) RND(15) RND(26) RND(6)   x0 += ks0; x1 += ks1 + 3u;
    RND(17) RND(29) RND(16) RND(24)  x0 += ks1; x1 += ks2 + 4u;
    RND(13) RND(15) RND(26) RND(6)   x0 += ks2; x1 += ks0 + 5u;
#undef RND
    return x0 ^ x1;
}

// -------- gather + finalize: one wave per node, 4-deep MLP ------------------
__global__ __launch_bounds__(256) void gather_kernel(const unsigned short* __restrict__ hp,
                                                     const float* __restrict__ x,
                                                     const int* __restrict__ off,
                                                     const int* __restrict__ adj,
                                                     const float* __restrict__ dis,
                                                     const float* __restrict__ b,
                                                     float* __restrict__ out, int N) {
    int wave = (int)((blockIdx.x * 256u + threadIdx.x) >> 6);
    if (wave >= N) return;
    const int lane = threadIdx.x & 63;
    const int node = wave;
    const float dn = dis[node];
    const int c0 = lane * 2;
    const unsigned short* hpc = hp + c0;

    unsigned hv = *(const unsigned*)(hpc + (size_t)node * NDIM);
    float ax0 = bf2f((unsigned short)hv), ay0 = bf2f((unsigned short)(hv >> 16));
    float ax1 = 0.f, ay1 = 0.f, ax2 = 0.f, ay2 = 0.f, ax3 = 0.f, ay3 = 0.f;

    int k0 = off[node], k1 = off[node + 1];
    int kbase = k0;
    while (kbase < k1) {
        int nb = k1 - kbase; if (nb > 64) nb = 64;
        int myadj = (kbase + lane < k1) ? adj[kbase + lane] : 0;
        int j = 0;
        for (; j + 4 <= nb; j += 4) {
            int s0 = __shfl(myadj, j);
            int s1 = __shfl(myadj, j + 1);
            int s2 = __shfl(myadj, j + 2);
            int s3 = __shfl(myadj, j + 3);
            unsigned v0 = *(const unsigned*)(hpc + (size_t)s0 * NDIM);
            unsigned v1 = *(const unsigned*)(hpc + (size_t)s1 * NDIM);
            unsigned v2 = *(const unsigned*)(hpc + (size_t)s2 * NDIM);
            unsigned v3 = *(const unsigned*)(hpc + (size_t)s3 * NDIM);
            ax0 += bf2f((unsigned short)v0); ay0 += bf2f((unsigned short)(v0 >> 16));
            ax1 += bf2f((unsigned short)v1); ay1 += bf2f((unsigned short)(v1 >> 16));
            ax2 += bf2f((unsigned short)v2); ay2 += bf2f((unsigned short)(v2 >> 16));
            ax3 += bf2f((unsigned short)v3); ay3 += bf2f((unsigned short)(v3 >> 16));
        }
        for (; j < nb; ++j) {
            int s = __shfl(myadj, j);
            unsigned v = *(const unsigned*)(hpc + (size_t)s * NDIM);
            ax0 += bf2f((unsigned short)v); ay0 += bf2f((unsigned short)(v >> 16));
        }
        kbase += nb;
    }

    float ax = (ax0 + ax1) + (ax2 + ax3);
    float ay = (ay0 + ay1) + (ay2 + ay3);

    float v0 = fmaxf(fmaf(dn, ax, b[c0]), 0.f);
    float v1 = fmaxf(fmaf(dn, ay, b[c0 + 1]), 0.f);

    unsigned i0 = (unsigned)(node * NDIM + c0);
    unsigned bb0 = tf_bits(i0);
    unsigned bb1 = tf_bits(i0 + 1u);
    v0 = (bb0 >> 31) ? 0.f : v0 * 2.f;
    v1 = (bb1 >> 31) ? 0.f : v1 * 2.f;

    float2 xr = ((const float2*)(x + (size_t)node * NDIM))[lane];
    float2 o;
    o.x = v0 + xr.x;
    o.y = v1 + xr.y;
    ((float2*)(out + (size_t)node * NDIM))[lane] = o;
}

extern "C" void kernel_launch(void* const* d_in, const int* in_sizes, int n_in,
                              void* d_out, int out_size, void* d_ws, size_t ws_size,
                              hipStream_t stream) {
    const float* x = (const float*)d_in[0];
    const unsigned* edge_w = (const unsigned*)d_in[1];
    const float* W = (const float*)d_in[2];
    const float* b = (const float*)d_in[3];
    float* out = (float*)d_out;

    const int N = in_sizes[0] / NDIM;          // 50000
    const int E = in_sizes[1] / 2;             // 625000
    const int nbuck = (N + (1 << BSH) - 1) >> BSH;   // 98
    const int chunk = (E + NB_A - 1) / NB_A;   // edges per bucketing block

    char* ws = (char*)d_ws;
    unsigned short* hp = (unsigned short*)ws;                             // N*128 bf16
    float* dis   = (float*)(ws + (size_t)N * NDIM * sizeof(short));       // N
    int*   off   = (int*)((char*)dis + (size_t)N * sizeof(float));        // N+1
    int*   adj   = (int*)((char*)off + (size_t)(N + 4) * sizeof(int));    // E
    unsigned* ebuf = (unsigned*)((char*)adj + (size_t)E * sizeof(int));   // E
    int*   hist  = (int*)((char*)ebuf + (size_t)E * sizeof(unsigned));    // nbuck*NB_A
    int*   btot  = (int*)((char*)hist + (size_t)128 * NB_A * sizeof(int));// nbuck
    int*   bbase = (int*)((char*)btot + (size_t)128 * sizeof(int));       // nbuck
    int*   flag  = (int*)((char*)bbase + (size_t)128 * sizeof(int));      // 1

    detect_kernel<<<1, 256, 0, stream>>>(edge_w, flag);
    hist_kernel<<<NB_A, 256, 0, stream>>>(edge_w, flag, hist, E, nbuck, chunk);
    scanhist_kernel<<<nbuck, 1024, 0, stream>>>(hist, btot, NB_A);
    scanbuck_kernel<<<1, 128, 0, stream>>>(btot, bbase, nbuck, off, N, E);
    bucket_kernel<<<NB_A, 256, 0, stream>>>(edge_w, flag, hist, bbase, ebuf, E, nbuck, chunk);
    csr_kernel<<<nbuck, 512, 0, stream>>>(ebuf, bbase, btot, adj, off, dis, N);

    gemm_kernel<<<(N + 63) / 64, 256, 0, stream>>>(x, W, dis, hp, N);

    gather_kernel<<<(N + 3) / 4, 256, 0, stream>>>(hp, x, off, adj, dis, b, out, N);
}